// Round 1
// 458.520 us; speedup vs baseline: 1.1023x; 1.1023x over previous
//
#include <hip/hip_runtime.h>

// Inputs fp32, OUTPUT fp32. N from in_sizes[3].
// ws use: 16 latent-accumulator slots strided 16 floats (64 B) = 1 KB.
//
// R1 changes vs 499us baseline:
//  - fast_tanh (exp2+rcp+copysign, ~7 ops) replaces tanhf (~35 ops incl. precise divide).
//    err ~1e-6 << threshold 9.45e-3 (current absmax 1.95e-3 is ref quantization).
//  - full static unrolling of every layer loop: VGPR_Count=36 + WRITE_SIZE=4x output
//    proved activation arrays were spilled to scratch (runtime-indexed locals).
//  - phaseC 32->48->16 tail streamed: g3 never materialized; peak live = a2[32]+a4[16].
//  - vectorized per-row loads (float2/float4).
#define TPB 256

typedef unsigned int uint;
typedef unsigned short ushort;

__device__ __forceinline__ float fast_tanh(float x) {
  // tanh(x) = sign(x) * (1 - e^{-2|x|}) / (1 + e^{-2|x|})
  const float ax = __builtin_fabsf(x);
  const float t  = __builtin_amdgcn_exp2f(-2.8853900817779268f * ax);  // e^{-2|x|}
  const float r  = (1.0f - t) * __builtin_amdgcn_rcpf(1.0f + t);
  return __builtin_copysignf(r, x);
}

// ---------- zero latent accumulator ----------
__global__ __launch_bounds__(256) void zero_kernel(float* ws) {
  ws[threadIdx.x] = 0.0f;
}

// ---------- phase A: literal per-row MLP 17->16->32->16, all tanh, sum-reduce ----------
__global__ __launch_bounds__(TPB, 4) void phaseA_kernel(
    const float* __restrict__ means, const float* __restrict__ cov,
    const float* __restrict__ uu,    const float* __restrict__ bnd,
    const float* __restrict__ su,    const float* __restrict__ sux,
    const float* __restrict__ suxx,  const float* __restrict__ spde,
    const float* __restrict__ lw1, const float* __restrict__ lb1,
    const float* __restrict__ lw2, const float* __restrict__ lb2,
    const float* __restrict__ lw3, const float* __restrict__ lb3,
    float* __restrict__ acc_out, int n) {
  const int tid = threadIdx.x;
  const int row = blockIdx.x * TPB + tid;
  const bool valid = row < n;
  const int r = valid ? row : 0;

  // params = concat([means(2), cov(4), u(1), b(1), su(1), sux(2), suxx(2), spde(4)])
  float x[17];
  { const float2 v = *(const float2*)(means + (size_t)r * 2); x[0] = v.x; x[1] = v.y; }
  { const float4 v = *(const float4*)(cov   + (size_t)r * 4); x[2] = v.x; x[3] = v.y; x[4] = v.z; x[5] = v.w; }
  x[6] = uu[r]; x[7] = bnd[r]; x[8] = su[r];
  { const float2 v = *(const float2*)(sux   + (size_t)r * 2); x[9]  = v.x; x[10] = v.y; }
  { const float2 v = *(const float2*)(suxx  + (size_t)r * 2); x[11] = v.x; x[12] = v.y; }
  { const float4 v = *(const float4*)(spde  + (size_t)r * 4); x[13] = v.x; x[14] = v.y; x[15] = v.z; x[16] = v.w; }

  float h1[16];
#pragma unroll
  for (int o = 0; o < 16; o++) {
    float s = lb1[o];
#pragma unroll
    for (int i = 0; i < 17; i++) s = fmaf(lw1[o * 17 + i], x[i], s);
    h1[o] = fast_tanh(s);
  }
  float h2[32];
#pragma unroll
  for (int o = 0; o < 32; o++) {
    float s = lb2[o];
#pragma unroll
    for (int i = 0; i < 16; i++) s = fmaf(lw2[o * 16 + i], h1[i], s);
    h2[o] = fast_tanh(s);
  }
  // layer 3 -> wave reduce -> per-block LDS reduce -> one atomic per component per block
  __shared__ float red[4][16];
  float acc[16];
#pragma unroll
  for (int o = 0; o < 16; o++) {
    float s = lb3[o];
#pragma unroll
    for (int i = 0; i < 32; i++) s = fmaf(lw3[o * 32 + i], h2[i], s);
    float v = valid ? fast_tanh(s) : 0.0f;
    v += __shfl_down(v, 32); v += __shfl_down(v, 16); v += __shfl_down(v, 8);
    v += __shfl_down(v, 4);  v += __shfl_down(v, 2);  v += __shfl_down(v, 1);
    acc[o] = v;
  }
  const int lane = tid & 63, wv = tid >> 6;
  if (lane == 0) {
#pragma unroll
    for (int o = 0; o < 16; o++) red[wv][o] = acc[o];
  }
  __syncthreads();
  if (tid < 16) {
    float s = red[0][tid] + red[1][tid] + red[2][tid] + red[3][tid];
    atomicAdd(&acc_out[tid * 16], s);  // 64 B apart: one cache line per component
  }
}

// ---------- phase C: in-block t-nets (literal), then literal per-row transform + MLP ----------
struct CArgs {
  const float* w1[5]; const float* b1[5];
  const float* w2[5]; const float* b2[5];
  const float* w3[5]; const float* b3[5];
};

__global__ __launch_bounds__(TPB, 4) void phaseC_kernel(
    CArgs ta,
    const float* __restrict__ cov,  const float* __restrict__ uu,
    const float* __restrict__ bnd,  const float* __restrict__ su,
    const float* __restrict__ sux,  const float* __restrict__ suxx,
    const float* __restrict__ spde, const float* __restrict__ ws,
    const float* __restrict__ jw1,  const float* __restrict__ jb1,
    const float* __restrict__ jw2,  const float* __restrict__ jb2,
    const float* __restrict__ jw3,  const float* __restrict__ jb3,
    const float* __restrict__ jw4,  const float* __restrict__ jb4,
    float* __restrict__ out, int n) {
  const int tid = threadIdx.x;
  __shared__ float lat[16];
  __shared__ float H1s[5][48];
  __shared__ float H2s[5][32];
  __shared__ float Tall[29];  // T(4)@0, Tu(1)@4, Tux(4)@5, Tuxx(4)@9, Tp(16)@13 (row-major dd x dd)

  if (tid < 16) lat[tid] = ws[tid * 16] * (1.0f / (float)n);
  __syncthreads();
  if (tid < 240) {  // _tnet layer 1: 16 -> 48, tanh
    int net = tid / 48, o = tid % 48;
    float s = ta.b1[net][o];
#pragma unroll
    for (int i = 0; i < 16; i++) s = fmaf(ta.w1[net][o * 16 + i], lat[i], s);
    H1s[net][o] = fast_tanh(s);
  }
  __syncthreads();
  if (tid < 160) {  // _tnet layer 2: 48 -> 32, tanh
    int net = tid / 32, o = tid % 32;
    float s = ta.b2[net][o];
#pragma unroll
    for (int i = 0; i < 48; i++) s = fmaf(ta.w2[net][o * 48 + i], H1s[net][i], s);
    H2s[net][o] = fast_tanh(s);
  }
  __syncthreads();
  if (tid < 29) {   // _tnet layer 3: 32 -> dd*dd, + eye(dd)
    int net, o, dd;
    if      (tid < 4)  { net = 0; o = tid;      dd = 2; }
    else if (tid < 5)  { net = 1; o = tid - 4;  dd = 1; }
    else if (tid < 9)  { net = 2; o = tid - 5;  dd = 2; }
    else if (tid < 13) { net = 3; o = tid - 9;  dd = 2; }
    else               { net = 4; o = tid - 13; dd = 4; }
    float s = ta.b3[net][o];
#pragma unroll
    for (int i = 0; i < 32; i++) s = fmaf(ta.w3[net][o * 32 + i], H2s[net][i], s);
    if (o / dd == o % dd) s += 1.0f;
    Tall[tid] = s;
  }
  __syncthreads();

  const int row = blockIdx.x * TPB + tid;
  if (row >= n) return;  // no further barriers below

  // ---- literal t_params ----
  const float4 c4 = *(const float4*)(cov + (size_t)row * 4);
  float tp[15];
  // t_cov[i,k] = sum_j T[i,j] * cov[j,k]
  tp[0] = Tall[0] * c4.x + Tall[1] * c4.z;
  tp[1] = Tall[0] * c4.y + Tall[1] * c4.w;
  tp[2] = Tall[2] * c4.x + Tall[3] * c4.z;
  tp[3] = Tall[2] * c4.y + Tall[3] * c4.w;
  tp[4] = Tall[4] * uu[row];          // t_u
  tp[5] = bnd[row];                   // b passthrough
  tp[6] = Tall[4] * su[row];          // t_su
  { const float2 v = *(const float2*)(sux + (size_t)row * 2);
    tp[7] = Tall[5] * v.x + Tall[6] * v.y;
    tp[8] = Tall[7] * v.x + Tall[8] * v.y; }
  { const float2 v = *(const float2*)(suxx + (size_t)row * 2);
    tp[9]  = Tall[9]  * v.x + Tall[10] * v.y;
    tp[10] = Tall[11] * v.x + Tall[12] * v.y; }
  { const float4 v = *(const float4*)(spde + (size_t)row * 4);
#pragma unroll
    for (int a = 0; a < 4; a++)
      tp[11 + a] = Tall[13 + a * 4] * v.x + Tall[13 + a * 4 + 1] * v.y +
                   Tall[13 + a * 4 + 2] * v.z + Tall[13 + a * 4 + 3] * v.w; }

  // ---- literal j-net: 15 -> 16 -> 32 -> 48 -> 16 ----
  float a1[16];
#pragma unroll
  for (int o = 0; o < 16; o++) {
    float s = jb1[o];
#pragma unroll
    for (int i = 0; i < 15; i++) s = fmaf(jw1[o * 15 + i], tp[i], s);
    a1[o] = fast_tanh(s);
  }
  float a2[32];
#pragma unroll
  for (int o = 0; o < 32; o++) {
    float s = jb2[o];
#pragma unroll
    for (int i = 0; i < 16; i++) s = fmaf(jw2[o * 16 + i], a1[i], s);
    a2[o] = fast_tanh(s);
  }
  // Streamed 32->48->16: never materialize g3[48]; peak live = a2[32]+a4[16].
  // Partial unroll keeps I-cache footprint small; o is wave-uniform so jw3/jw4
  // accesses stay scalar loads.
  float a4[16];
#pragma unroll
  for (int j = 0; j < 16; j++) a4[j] = jb4[j];
#pragma unroll 8
  for (int o = 0; o < 48; o++) {
    float s = jb3[o];
#pragma unroll
    for (int i = 0; i < 32; i++) s = fmaf(jw3[o * 32 + i], a2[i], s);
    const float h = fast_tanh(s);
#pragma unroll
    for (int j = 0; j < 16; j++) a4[j] = fmaf(jw4[j * 48 + o], h, a4[j]);
  }
  float4* p = (float4*)(out + (size_t)row * 16);
  p[0] = make_float4(a4[0],  a4[1],  a4[2],  a4[3]);
  p[1] = make_float4(a4[4],  a4[5],  a4[6],  a4[7]);
  p[2] = make_float4(a4[8],  a4[9],  a4[10], a4[11]);
  p[3] = make_float4(a4[12], a4[13], a4[14], a4[15]);
}

// ---------- launch ----------
extern "C" void kernel_launch(void* const* d_in, const int* in_sizes, int n_in,
                              void* d_out, int out_size, void* d_ws, size_t ws_size,
                              hipStream_t stream) {
  float* ws = (float*)d_ws;
  const int n = in_sizes[3];              // boundaries: (N,)
  const int nblk = (n + TPB - 1) / TPB;

  zero_kernel<<<1, 256, 0, stream>>>(ws);

  phaseA_kernel<<<nblk, TPB, 0, stream>>>(
      (const float*)d_in[0], (const float*)d_in[1], (const float*)d_in[2],
      (const float*)d_in[3], (const float*)d_in[4], (const float*)d_in[5],
      (const float*)d_in[6], (const float*)d_in[7],
      (const float*)d_in[8], (const float*)d_in[9], (const float*)d_in[10],
      (const float*)d_in[11], (const float*)d_in[12], (const float*)d_in[13],
      ws, n);

  CArgs ca;
  for (int k = 0; k < 5; k++) {
    int b = 14 + 6 * k;
    ca.w1[k] = (const float*)d_in[b];     ca.b1[k] = (const float*)d_in[b + 1];
    ca.w2[k] = (const float*)d_in[b + 2]; ca.b2[k] = (const float*)d_in[b + 3];
    ca.w3[k] = (const float*)d_in[b + 4]; ca.b3[k] = (const float*)d_in[b + 5];
  }

  phaseC_kernel<<<nblk, TPB, 0, stream>>>(
      ca,
      (const float*)d_in[1], (const float*)d_in[2], (const float*)d_in[3],
      (const float*)d_in[4], (const float*)d_in[5], (const float*)d_in[6],
      (const float*)d_in[7], ws,
      (const float*)d_in[44], (const float*)d_in[45],
      (const float*)d_in[46], (const float*)d_in[47],
      (const float*)d_in[48], (const float*)d_in[49],
      (const float*)d_in[50], (const float*)d_in[51],
      (float*)d_out, n);
}